// Round 7
// baseline (582.675 us; speedup 1.0000x reference)
//
#include <hip/hip_runtime.h>
#include <math.h>

typedef __bf16 bf16_t;
typedef __bf16 bf16x8 __attribute__((ext_vector_type(8)));
typedef __bf16 bf16x4 __attribute__((ext_vector_type(4)));
typedef float  f32x4  __attribute__((ext_vector_type(4)));

#define NHEAD 16
#define HDIM 64
#define DMODEL 1024
#define TSEQ 2048

// raw barrier + explicit waitcnt: avoids __syncthreads()'s vmcnt(0) drain,
// so prefetch loads stay in flight across the barrier.
#define LGKM0() do { asm volatile("s_waitcnt lgkmcnt(0)" ::: "memory"); \
                     __builtin_amdgcn_sched_barrier(0); } while (0)
#define SBAR() __builtin_amdgcn_s_barrier()

__device__ __forceinline__ f32x4 mfma16(bf16x8 a, bf16x8 b, f32x4 c) {
  return __builtin_amdgcn_mfma_f32_16x16x32_bf16(a, b, c, 0, 0, 0);
}

// pack two f32 -> (bf16(hi)<<16)|bf16(lo)
__device__ __forceinline__ unsigned pk2(float lo, float hi) {
  unsigned short a = __builtin_bit_cast(unsigned short, (__bf16)lo);
  unsigned short c = __builtin_bit_cast(unsigned short, (__bf16)hi);
  return ((unsigned)c << 16) | a;
}

// split two f32x4 into hi/lo bf16x8 and store to frag-major LDS slot
__device__ __forceinline__ void cvtstore(f32x4 x0, f32x4 x1, bf16_t* dh, bf16_t* dl, int off) {
  bf16x8 hfr, lfr;
#pragma unroll
  for (int j = 0; j < 4; ++j) {
    float v = x0[j];
    __bf16 hb = (__bf16)v;
    hfr[j] = hb; lfr[j] = (__bf16)(v - (float)hb);
    float w = x1[j];
    __bf16 wb = (__bf16)w;
    hfr[4 + j] = wb; lfr[4 + j] = (__bf16)(w - (float)wb);
  }
  *(bf16x8*)(dh + off) = hfr;
  *(bf16x8*)(dl + off) = lfr;
}

// ---------------- bias table: BM[b][q][k] = alpha*copysign(log1p|df|,df) + amask[q][k] (+ -1e30 if kpm) ----------------
__global__ __launch_bounds__(256)
void build_bias(const float* __restrict__ amask, const unsigned char* __restrict__ kpm,
                const float* __restrict__ sf, const float* __restrict__ alpha_p,
                bf16_t* __restrict__ BM) {
  size_t idx = (size_t)blockIdx.x * 256 + threadIdx.x;
  int k8 = (int)(idx & (TSEQ / 8 - 1));
  size_t bq = idx >> 8;
  int b = (int)(bq >> 11);
  int q = (int)(bq & (TSEQ - 1));
  const float sfq = sf[bq];
  const float alpha = *alpha_p;
  const float* sfk = sf + (size_t)b * TSEQ + k8 * 8;
  const float* am  = amask + (size_t)q * TSEQ + k8 * 8;
  const unsigned char* kp = kpm + (size_t)b * TSEQ + k8 * 8;
  bf16x8 o;
#pragma unroll
  for (int j = 0; j < 8; ++j) {
    float df = sfq - sfk[j];
    float v = alpha * copysignf(log1pf(fabsf(df)), df) + am[j];
    if (kp[j]) v = -1.0e30f;
    o[j] = (__bf16)v;
  }
  *(bf16x8*)&BM[idx * 8] = o;
}

// ---------------- GEMM: C = A @ W^T + bias via bf16x3 split MFMA ----------------
// MODE 0: f32 out [M][1024]; MODE 1: bf16 hi/lo head layout [b][h][t][d]; MODE 2: V transposed [b][h][d][t]
template<int MODE>
__global__ __launch_bounds__(256)
void gemm_mfma(const float* __restrict__ A, const float* __restrict__ W,
               const float* __restrict__ bias,
               bf16_t* __restrict__ obh, bf16_t* __restrict__ obl,
               float* __restrict__ of) {
  __shared__ bf16_t AH[8 * 512], AL[8 * 512], WH[4 * 512], WL[4 * 512];
  const int tid = threadIdx.x;
  const int lane = tid & 63;
  const int a15 = lane & 15, g = lane >> 4;
  const int wv = tid >> 6, wm = wv >> 1, wn = wv & 1;
  const int m0 = blockIdx.y * 128, n0 = blockIdx.x * 64;
  constexpr int NI = (MODE == 2) ? 2 : 4;
  constexpr int NJ = (MODE == 2) ? 4 : 2;
  f32x4 acc[NI][NJ] = {};

  const int s0 = tid, s1 = tid + 256;
  const int t0 = s0 >> 6, l0 = s0 & 63;
  const int t1 = s1 >> 6, l1 = s1 & 63;
  const float* pA0 = A + (size_t)(m0 + t0 * 16 + (l0 & 15)) * DMODEL + 8 * (l0 >> 4);
  const float* pA1 = A + (size_t)(m0 + t1 * 16 + (l1 & 15)) * DMODEL + 8 * (l1 >> 4);
  const float* pW  = W + (size_t)(n0 + t0 * 16 + (l0 & 15)) * DMODEL + 8 * (l0 >> 4);

  f32x4 rA0a = *(const f32x4*)pA0, rA0b = *(const f32x4*)(pA0 + 4);
  f32x4 rA1a = *(const f32x4*)pA1, rA1b = *(const f32x4*)(pA1 + 4);
  f32x4 rWa  = *(const f32x4*)pW,  rWb  = *(const f32x4*)(pW + 4);

  for (int k0 = 0; k0 < DMODEL; k0 += 32) {
    SBAR();                          // prior step's LDS reads consumed (raw: no vmem drain)
    cvtstore(rA0a, rA0b, AH, AL, s0 * 8);
    cvtstore(rA1a, rA1b, AH, AL, s1 * 8);
    cvtstore(rWa,  rWb,  WH, WL, s0 * 8);
    __builtin_amdgcn_sched_barrier(0);
    if (k0 + 32 < DMODEL) {          // prefetch next K-step; survives the barriers below
      pA0 += 32; pA1 += 32; pW += 32;
      rA0a = *(const f32x4*)pA0; rA0b = *(const f32x4*)(pA0 + 4);
      rA1a = *(const f32x4*)pA1; rA1b = *(const f32x4*)(pA1 + 4);
      rWa  = *(const f32x4*)pW;  rWb  = *(const f32x4*)(pW + 4);
    }
    LGKM0();                         // ds_writes committed
    SBAR();

    bf16x8 ah[4], al[4], wh[2], wl[2];
#pragma unroll
    for (int i = 0; i < 4; ++i) {
      ah[i] = *(const bf16x8*)&AH[(wm * 4 + i) * 512 + lane * 8];
      al[i] = *(const bf16x8*)&AL[(wm * 4 + i) * 512 + lane * 8];
    }
#pragma unroll
    for (int j = 0; j < 2; ++j) {
      wh[j] = *(const bf16x8*)&WH[(wn * 2 + j) * 512 + lane * 8];
      wl[j] = *(const bf16x8*)&WL[(wn * 2 + j) * 512 + lane * 8];
    }
    __builtin_amdgcn_s_setprio(1);
    if (MODE == 2) {
#pragma unroll
      for (int i = 0; i < 2; ++i)
#pragma unroll
        for (int j = 0; j < 4; ++j) {
          acc[i][j] = mfma16(wh[i], ah[j], acc[i][j]);
          acc[i][j] = mfma16(wh[i], al[j], acc[i][j]);
          acc[i][j] = mfma16(wl[i], ah[j], acc[i][j]);
        }
    } else {
#pragma unroll
      for (int i = 0; i < 4; ++i)
#pragma unroll
        for (int j = 0; j < 2; ++j) {
          acc[i][j] = mfma16(ah[i], wh[j], acc[i][j]);
          acc[i][j] = mfma16(ah[i], wl[j], acc[i][j]);
          acc[i][j] = mfma16(al[i], wh[j], acc[i][j]);
        }
    }
    __builtin_amdgcn_s_setprio(0);
  }

  if (MODE == 0) {
#pragma unroll
    for (int i = 0; i < 4; ++i)
#pragma unroll
      for (int j = 0; j < 2; ++j) {
        int n = n0 + wn * 32 + j * 16 + a15;
        float bs = bias[n];
#pragma unroll
        for (int r = 0; r < 4; ++r) {
          int m = m0 + wm * 64 + i * 16 + 4 * g + r;
          of[(size_t)m * DMODEL + n] = acc[i][j][r] + bs;
        }
      }
  } else if (MODE == 1) {
#pragma unroll
    for (int i = 0; i < 4; ++i)
#pragma unroll
      for (int j = 0; j < 2; ++j) {
        int n = n0 + wn * 32 + j * 16 + a15;
        float bs = bias[n];
        int hh = n >> 6, d = n & 63;
#pragma unroll
        for (int r = 0; r < 4; ++r) {
          int m = m0 + wm * 64 + i * 16 + 4 * g + r;
          int bb = m >> 11, t = m & (TSEQ - 1);
          float v = acc[i][j][r] + bs;
          size_t o = (((size_t)(bb * NHEAD + hh)) * TSEQ + t) * HDIM + d;
          __bf16 hb = (__bf16)v;
          obh[o] = hb;
          obl[o] = (__bf16)(v - (float)hb);
        }
      }
  } else {
#pragma unroll
    for (int i = 0; i < 2; ++i)
#pragma unroll
      for (int j = 0; j < 4; ++j) {
        int m = m0 + wm * 64 + j * 16 + a15;
        int bb = m >> 11, t = m & (TSEQ - 1);
#pragma unroll
        for (int r = 0; r < 4; ++r) {
          int n = n0 + wn * 32 + i * 16 + 4 * g + r;
          float v = acc[i][j][r] + bias[n];
          int hh = n >> 6, d = n & 63;
          size_t o = (((size_t)(bb * NHEAD + hh)) * HDIM + d) * TSEQ + t;
          __bf16 hb = (__bf16)v;
          obh[o] = hb;
          obl[o] = (__bf16)(v - (float)hb);
        }
      }
  }
}

// ---------------- Flash attention: single 32KB LDS buffer, reg-staged split prefetch, raw barriers ----------------
// NO waves-per-EU hint: R4 (256,4) and R5 (256,3) pinned VGPR to 64/68 and spilled ~900MB
// to scratch. Unhinted, the compiler allocates ~130 VGPR with zero spill -> ~3 blocks/CU
// (32KB LDS allows 5; VGPR is the binding limit), 1.5x the occupancy of the 64KB dbuf version.
__global__ __launch_bounds__(256)
void attn_mfma(const bf16_t* __restrict__ Qhi, const bf16_t* __restrict__ Qlo,
               const bf16_t* __restrict__ Khi, const bf16_t* __restrict__ Klo,
               const bf16_t* __restrict__ Vth, const bf16_t* __restrict__ Vtl,
               const bf16_t* __restrict__ BMt, float* __restrict__ O) {
  __shared__ bf16_t KH[8 * 512], KL[8 * 512], VH[8 * 512], VL[8 * 512];  // 32 KiB
  const int tid = threadIdx.x;
  const int lane = tid & 63, wv = tid >> 6;
  const int a15 = lane & 15, g = lane >> 4;
  const int b = blockIdx.z, h = blockIdx.y, q0 = blockIdx.x * 64;
  const int bh = b * NHEAD + h;
  const int qg = q0 + wv * 16 + a15;
  constexpr int NT = TSEQ / 64;

  const bf16_t* Qh_b = Qhi + ((size_t)bh * TSEQ + qg) * HDIM;
  const bf16_t* Ql_b = Qlo + ((size_t)bh * TSEQ + qg) * HDIM;
  // staging bases: this thread loads rows 16*wv+a15 (x2 k-chunks of 32)
  const bf16_t* Kh_s = Khi + (size_t)bh * TSEQ * HDIM + (size_t)(16 * wv + a15) * HDIM + 8 * g;
  const bf16_t* Kl_s = Klo + (size_t)bh * TSEQ * HDIM + (size_t)(16 * wv + a15) * HDIM + 8 * g;
  const bf16_t* Vh_s = Vth + (size_t)bh * HDIM * TSEQ + (size_t)(16 * wv + a15) * TSEQ + 8 * g;
  const bf16_t* Vl_s = Vtl + (size_t)bh * HDIM * TSEQ + (size_t)(16 * wv + a15) * TSEQ + 8 * g;
  const bf16_t* bmrow = BMt + ((size_t)b * TSEQ + qg) * TSEQ;

  bf16x8 qh[2], ql[2];
  qh[0] = *(const bf16x8*)&Qh_b[8 * g];
  qh[1] = *(const bf16x8*)&Qh_b[32 + 8 * g];
  ql[0] = *(const bf16x8*)&Ql_b[8 * g];
  ql[1] = *(const bf16x8*)&Ql_b[32 + 8 * g];

  f32x4 aco[4] = {};
  float m_run = -3.0e38f, l_run = 0.f;

  uint4 rg[8];
  bf16x4 bmv[4], bmn[4];

  // prologue: stage tile 0 into regs
#pragma unroll
  for (int mt = 0; mt < 4; ++mt) bmv[mt] = *(const bf16x4*)&bmrow[16 * mt + 4 * g];
#pragma unroll
  for (int c = 0; c < 2; ++c) {
    rg[0 + c] = *(const uint4*)(Kh_s + 32 * c);
    rg[2 + c] = *(const uint4*)(Kl_s + 32 * c);
    rg[4 + c] = *(const uint4*)(Vh_s + 32 * c);
    rg[6 + c] = *(const uint4*)(Vl_s + 32 * c);
  }

  for (int t = 0; t < NT; ++t) {
    // --- write tile t into LDS (auto vmcnt-wait on rg) ---
#pragma unroll
    for (int c = 0; c < 2; ++c) {
      int sb = wv * 2 + c;
      *(uint4*)&KH[sb * 512 + lane * 8] = rg[0 + c];
      *(uint4*)&KL[sb * 512 + lane * 8] = rg[2 + c];
      *(uint4*)&VH[sb * 512 + lane * 8] = rg[4 + c];
      *(uint4*)&VL[sb * 512 + lane * 8] = rg[6 + c];
    }
    __builtin_amdgcn_sched_barrier(0);
    const int kn = (t + 1) * 64;
    if (t + 1 < NT) {                // K prefetch for t+1 (bias first: its wait won't drain K/V)
#pragma unroll
      for (int mt = 0; mt < 4; ++mt) bmn[mt] = *(const bf16x4*)&bmrow[kn + 16 * mt + 4 * g];
#pragma unroll
      for (int c = 0; c < 2; ++c) {
        rg[0 + c] = *(const uint4*)(Kh_s + (size_t)kn * HDIM + 32 * c);
        rg[2 + c] = *(const uint4*)(Kl_s + (size_t)kn * HDIM + 32 * c);
      }
    }
    LGKM0();                         // ds_writes committed; global loads stay in flight
    SBAR();

    // --- S^T = K·Q (3-way split) ---
    f32x4 s4[4];
    __builtin_amdgcn_s_setprio(1);
#pragma unroll
    for (int mt = 0; mt < 4; ++mt) {
      bf16x8 k0h = *(const bf16x8*)&KH[(mt * 2 + 0) * 512 + lane * 8];
      bf16x8 k1h = *(const bf16x8*)&KH[(mt * 2 + 1) * 512 + lane * 8];
      bf16x8 k0l = *(const bf16x8*)&KL[(mt * 2 + 0) * 512 + lane * 8];
      bf16x8 k1l = *(const bf16x8*)&KL[(mt * 2 + 1) * 512 + lane * 8];
      f32x4 sa = {};
      sa = mfma16(k0h, qh[0], sa);
      sa = mfma16(k1h, qh[1], sa);
      sa = mfma16(k0h, ql[0], sa);
      sa = mfma16(k1h, ql[1], sa);
      sa = mfma16(k0l, qh[0], sa);
      sa = mfma16(k1l, qh[1], sa);
      s4[mt] = sa;
    }
    __builtin_amdgcn_s_setprio(0);
    __builtin_amdgcn_sched_barrier(0);
    if (t + 1 < NT) {                // V prefetch for t+1 (issued under softmax+PV)
#pragma unroll
      for (int c = 0; c < 2; ++c) {
        rg[4 + c] = *(const uint4*)(Vh_s + kn + 32 * c);
        rg[6 + c] = *(const uint4*)(Vl_s + kn + 32 * c);
      }
    }

    // --- scores: fma with precomputed bias+mask table ---
#pragma unroll
    for (int mt = 0; mt < 4; ++mt)
#pragma unroll
      for (int r = 0; r < 4; ++r)
        s4[mt][r] = fmaf(s4[mt][r], 0.125f, (float)bmv[mt][r]);

    // --- online softmax with defer-rescale (T13) ---
    float tmax = -3.0e38f;
#pragma unroll
    for (int mt = 0; mt < 4; ++mt)
#pragma unroll
      for (int r = 0; r < 4; ++r) tmax = fmaxf(tmax, s4[mt][r]);
    tmax = fmaxf(tmax, __shfl_xor(tmax, 16));
    tmax = fmaxf(tmax, __shfl_xor(tmax, 32));
    if (!__all(tmax - m_run <= 8.0f)) {
      float mnew = fmaxf(m_run, tmax);
      float corr = __expf(m_run - mnew);
      l_run *= corr;
#pragma unroll
      for (int dt = 0; dt < 4; ++dt) aco[dt] *= corr;
      m_run = mnew;
    }
    float psum = 0.f;
    unsigned pk01[4], pk23[4];
#pragma unroll
    for (int mt = 0; mt < 4; ++mt) {
      float p0 = __expf(s4[mt][0] - m_run);
      float p1 = __expf(s4[mt][1] - m_run);
      float p2 = __expf(s4[mt][2] - m_run);
      float p3 = __expf(s4[mt][3] - m_run);
      psum += (p0 + p1) + (p2 + p3);
      pk01[mt] = pk2(p0, p1);
      pk23[mt] = pk2(p2, p3);
    }
    psum += __shfl_xor(psum, 16);
    psum += __shfl_xor(psum, 32);
    l_run += psum;

    // --- P -> B-frag layout: slot (g,j) holds key 32ks+8g+j of row q=a15 ---
    bf16x8 pf[2];
#pragma unroll
    for (int ks = 0; ks < 2; ++ks) {
      int src0 = a15 + 16 * (2 * (g & 1));
      int src1 = src0 + 16;
      unsigned A0 = __shfl(pk01[2 * ks + 0], src0), A1 = __shfl(pk01[2 * ks + 1], src0);
      unsigned B0 = __shfl(pk23[2 * ks + 0], src0), B1 = __shfl(pk23[2 * ks + 1], src0);
      unsigned C0 = __shfl(pk01[2 * ks + 0], src1), C1 = __shfl(pk01[2 * ks + 1], src1);
      unsigned D0 = __shfl(pk23[2 * ks + 0], src1), D1 = __shfl(pk23[2 * ks + 1], src1);
      bool hi2 = (g >> 1) & 1;
      uint4 wds;
      wds.x = hi2 ? A1 : A0;
      wds.y = hi2 ? B1 : B0;
      wds.z = hi2 ? C1 : C0;
      wds.w = hi2 ? D1 : D0;
      pf[ks] = __builtin_bit_cast(bf16x8, wds);
    }

    // --- O^T += Vt · P (V split hi/lo) ---
    __builtin_amdgcn_s_setprio(1);
#pragma unroll
    for (int dt = 0; dt < 4; ++dt) {
#pragma unroll
      for (int ks = 0; ks < 2; ++ks) {
        bf16x8 vh = *(const bf16x8*)&VH[(dt * 2 + ks) * 512 + lane * 8];
        bf16x8 vl = *(const bf16x8*)&VL[(dt * 2 + ks) * 512 + lane * 8];
        aco[dt] = mfma16(vh, pf[ks], aco[dt]);
        aco[dt] = mfma16(vl, pf[ks], aco[dt]);
      }
    }
    __builtin_amdgcn_s_setprio(0);

    if (t + 1 < NT) {
#pragma unroll
      for (int mt = 0; mt < 4; ++mt) bmv[mt] = bmn[mt];
    }
    SBAR();                          // all waves done reading LDS before next overwrite
  }

  float inv = 1.0f / l_run;
#pragma unroll
  for (int dt = 0; dt < 4; ++dt) {
    f32x4 o = aco[dt] * inv;
    *(f32x4*)&O[((size_t)b * TSEQ + qg) * DMODEL + h * HDIM + dt * 16 + 4 * g] = o;
  }
}

extern "C" void kernel_launch(void* const* d_in, const int* in_sizes, int n_in,
                              void* d_out, int out_size, void* d_ws, size_t ws_size,
                              hipStream_t stream) {
  const float* query = (const float*)d_in[0];
  const float* key = (const float*)d_in[1];
  const float* value = (const float*)d_in[2];
  const unsigned char* kpm = (const unsigned char*)d_in[3];
  const float* amask = (const float*)d_in[4];
  const float* sf = (const float*)d_in[5];
  const float* Wq = (const float*)d_in[6];
  const float* bq = (const float*)d_in[7];
  const float* Wk = (const float*)d_in[8];
  const float* bk = (const float*)d_in[9];
  const float* Wv = (const float*)d_in[10];
  const float* bv = (const float*)d_in[11];
  const float* Wo = (const float*)d_in[12];
  const float* bo = (const float*)d_in[13];
  const float* alpha = (const float*)d_in[14];
  float* out = (float*)d_out;

  const size_t NEL = (size_t)2 * NHEAD * TSEQ * HDIM;  // 4,194,304 per bf16 array
  bf16_t* p = (bf16_t*)d_ws;
  bf16_t* Qh = p;
  bf16_t* Ql = p + NEL;
  bf16_t* Kh = p + 2 * NEL;
  bf16_t* Kl = p + 3 * NEL;
  bf16_t* Vh = p + 4 * NEL;
  bf16_t* Vl = p + 5 * NEL;
  float* Oa = (float*)(p + 6 * NEL);                    // 16.8 MB
  bf16_t* BMt = (bf16_t*)(Oa + (size_t)4096 * DMODEL);  // 16.8 MB  (total 80 MiB)

  dim3 bb(256);
  build_bias<<<dim3(4096), bb, 0, stream>>>(amask, kpm, sf, alpha, BMt);

  dim3 gg(16, 32);
  gemm_mfma<1><<<gg, bb, 0, stream>>>(query, Wq, bq, Qh, Ql, nullptr);
  gemm_mfma<1><<<gg, bb, 0, stream>>>(key, Wk, bk, Kh, Kl, nullptr);
  gemm_mfma<2><<<gg, bb, 0, stream>>>(value, Wv, bv, Vh, Vl, nullptr);
  dim3 ga(TSEQ / 64, NHEAD, 2);
  attn_mfma<<<ga, bb, 0, stream>>>(Qh, Ql, Kh, Kl, Vh, Vl, BMt, Oa);
  gemm_mfma<0><<<gg, bb, 0, stream>>>(Oa, Wo, bo, nullptr, nullptr, out);
}

// Round 8
// 339.877 us; speedup vs baseline: 1.7144x; 1.7144x over previous
//
#include <hip/hip_runtime.h>
#include <math.h>

typedef __bf16 bf16_t;
typedef __bf16 bf16x8 __attribute__((ext_vector_type(8)));
typedef __bf16 bf16x4 __attribute__((ext_vector_type(4)));
typedef float  f32x4  __attribute__((ext_vector_type(4)));

#define NHEAD 16
#define HDIM 64
#define DMODEL 1024
#define TSEQ 2048

#define SBAR() __builtin_amdgcn_s_barrier()
#define LGKM0() do { asm volatile("s_waitcnt lgkmcnt(0)" ::: "memory"); \
                     __builtin_amdgcn_sched_barrier(0); } while (0)

__device__ __forceinline__ f32x4 mfma16(bf16x8 a, bf16x8 b, f32x4 c) {
  return __builtin_amdgcn_mfma_f32_16x16x32_bf16(a, b, c, 0, 0, 0);
}

// async global->LDS, 16B per lane; lds base wave-uniform (HW adds lane*16)
__device__ __forceinline__ void gload16(const bf16_t* g, bf16_t* l) {
  __builtin_amdgcn_global_load_lds((const __attribute__((address_space(1))) void*)g,
                                   (__attribute__((address_space(3))) void*)l, 16, 0, 0);
}

// pack two f32 -> (bf16(hi)<<16)|bf16(lo)
__device__ __forceinline__ unsigned pk2(float lo, float hi) {
  unsigned short a = __builtin_bit_cast(unsigned short, (__bf16)lo);
  unsigned short c = __builtin_bit_cast(unsigned short, (__bf16)hi);
  return ((unsigned)c << 16) | a;
}

// split two f32x4 into hi/lo bf16x8 and store to frag-major LDS slot
__device__ __forceinline__ void cvtstore(f32x4 x0, f32x4 x1, bf16_t* dh, bf16_t* dl, int off) {
  bf16x8 hfr, lfr;
#pragma unroll
  for (int j = 0; j < 4; ++j) {
    float v = x0[j];
    __bf16 hb = (__bf16)v;
    hfr[j] = hb; lfr[j] = (__bf16)(v - (float)hb);
    float w = x1[j];
    __bf16 wb = (__bf16)w;
    hfr[4 + j] = wb; lfr[4 + j] = (__bf16)(w - (float)wb);
  }
  *(bf16x8*)(dh + off) = hfr;
  *(bf16x8*)(dl + off) = lfr;
}

// ---------------- bias table: BM[b][q][k] = alpha*copysign(log1p|df|,df) + amask[q][k] (+ -1e30 if kpm) ----------------
__global__ __launch_bounds__(256)
void build_bias(const float* __restrict__ amask, const unsigned char* __restrict__ kpm,
                const float* __restrict__ sf, const float* __restrict__ alpha_p,
                bf16_t* __restrict__ BM) {
  size_t idx = (size_t)blockIdx.x * 256 + threadIdx.x;
  int k8 = (int)(idx & (TSEQ / 8 - 1));
  size_t bq = idx >> 8;
  int b = (int)(bq >> 11);
  int q = (int)(bq & (TSEQ - 1));
  const float sfq = sf[bq];
  const float alpha = *alpha_p;
  const float* sfk = sf + (size_t)b * TSEQ + k8 * 8;
  const float* am  = amask + (size_t)q * TSEQ + k8 * 8;
  const unsigned char* kp = kpm + (size_t)b * TSEQ + k8 * 8;
  bf16x8 o;
#pragma unroll
  for (int j = 0; j < 8; ++j) {
    float df = sfq - sfk[j];
    float v = alpha * copysignf(log1pf(fabsf(df)), df) + am[j];
    if (kp[j]) v = -1.0e30f;
    o[j] = (__bf16)v;
  }
  *(bf16x8*)&BM[idx * 8] = o;
}

// ---------------- GEMM: C = A @ W^T + bias via bf16x3 split MFMA ----------------
// MODE 0: f32 out [M][1024]; MODE 1: bf16 hi/lo head layout [b][h][t][d]; MODE 2: V transposed [b][h][d][t]
template<int MODE>
__global__ __launch_bounds__(256)
void gemm_mfma(const float* __restrict__ A, const float* __restrict__ W,
               const float* __restrict__ bias,
               bf16_t* __restrict__ obh, bf16_t* __restrict__ obl,
               float* __restrict__ of) {
  __shared__ bf16_t AH[8 * 512], AL[8 * 512], WH[4 * 512], WL[4 * 512];
  const int tid = threadIdx.x;
  const int lane = tid & 63;
  const int a15 = lane & 15, g = lane >> 4;
  const int wv = tid >> 6, wm = wv >> 1, wn = wv & 1;
  const int m0 = blockIdx.y * 128, n0 = blockIdx.x * 64;
  constexpr int NI = (MODE == 2) ? 2 : 4;
  constexpr int NJ = (MODE == 2) ? 4 : 2;
  f32x4 acc[NI][NJ] = {};

  const int s0 = tid, s1 = tid + 256;
  const int t0 = s0 >> 6, l0 = s0 & 63;
  const int t1 = s1 >> 6, l1 = s1 & 63;
  const float* pA0 = A + (size_t)(m0 + t0 * 16 + (l0 & 15)) * DMODEL + 8 * (l0 >> 4);
  const float* pA1 = A + (size_t)(m0 + t1 * 16 + (l1 & 15)) * DMODEL + 8 * (l1 >> 4);
  const float* pW  = W + (size_t)(n0 + t0 * 16 + (l0 & 15)) * DMODEL + 8 * (l0 >> 4);

  f32x4 rA0a = *(const f32x4*)pA0, rA0b = *(const f32x4*)(pA0 + 4);
  f32x4 rA1a = *(const f32x4*)pA1, rA1b = *(const f32x4*)(pA1 + 4);
  f32x4 rWa  = *(const f32x4*)pW,  rWb  = *(const f32x4*)(pW + 4);

  for (int k0 = 0; k0 < DMODEL; k0 += 32) {
    SBAR();                          // prior step's LDS reads consumed (raw: no vmem drain)
    cvtstore(rA0a, rA0b, AH, AL, s0 * 8);
    cvtstore(rA1a, rA1b, AH, AL, s1 * 8);
    cvtstore(rWa,  rWb,  WH, WL, s0 * 8);
    __builtin_amdgcn_sched_barrier(0);
    if (k0 + 32 < DMODEL) {          // prefetch next K-step; survives the barriers below
      pA0 += 32; pA1 += 32; pW += 32;
      rA0a = *(const f32x4*)pA0; rA0b = *(const f32x4*)(pA0 + 4);
      rA1a = *(const f32x4*)pA1; rA1b = *(const f32x4*)(pA1 + 4);
      rWa  = *(const f32x4*)pW;  rWb  = *(const f32x4*)(pW + 4);
    }
    LGKM0();                         // ds_writes committed
    SBAR();

    bf16x8 ah[4], al[4], wh[2], wl[2];
#pragma unroll
    for (int i = 0; i < 4; ++i) {
      ah[i] = *(const bf16x8*)&AH[(wm * 4 + i) * 512 + lane * 8];
      al[i] = *(const bf16x8*)&AL[(wm * 4 + i) * 512 + lane * 8];
    }
#pragma unroll
    for (int j = 0; j < 2; ++j) {
      wh[j] = *(const bf16x8*)&WH[(wn * 2 + j) * 512 + lane * 8];
      wl[j] = *(const bf16x8*)&WL[(wn * 2 + j) * 512 + lane * 8];
    }
    __builtin_amdgcn_s_setprio(1);
    if (MODE == 2) {
#pragma unroll
      for (int i = 0; i < 2; ++i)
#pragma unroll
        for (int j = 0; j < 4; ++j) {
          acc[i][j] = mfma16(wh[i], ah[j], acc[i][j]);
          acc[i][j] = mfma16(wh[i], al[j], acc[i][j]);
          acc[i][j] = mfma16(wl[i], ah[j], acc[i][j]);
        }
    } else {
#pragma unroll
      for (int i = 0; i < 4; ++i)
#pragma unroll
        for (int j = 0; j < 2; ++j) {
          acc[i][j] = mfma16(ah[i], wh[j], acc[i][j]);
          acc[i][j] = mfma16(ah[i], wl[j], acc[i][j]);
          acc[i][j] = mfma16(al[i], wh[j], acc[i][j]);
        }
    }
    __builtin_amdgcn_s_setprio(0);
  }

  if (MODE == 0) {
#pragma unroll
    for (int i = 0; i < 4; ++i)
#pragma unroll
      for (int j = 0; j < 2; ++j) {
        int n = n0 + wn * 32 + j * 16 + a15;
        float bs = bias[n];
#pragma unroll
        for (int r = 0; r < 4; ++r) {
          int m = m0 + wm * 64 + i * 16 + 4 * g + r;
          of[(size_t)m * DMODEL + n] = acc[i][j][r] + bs;
        }
      }
  } else if (MODE == 1) {
#pragma unroll
    for (int i = 0; i < 4; ++i)
#pragma unroll
      for (int j = 0; j < 2; ++j) {
        int n = n0 + wn * 32 + j * 16 + a15;
        float bs = bias[n];
        int hh = n >> 6, d = n & 63;
#pragma unroll
        for (int r = 0; r < 4; ++r) {
          int m = m0 + wm * 64 + i * 16 + 4 * g + r;
          int bb = m >> 11, t = m & (TSEQ - 1);
          float v = acc[i][j][r] + bs;
          size_t o = (((size_t)(bb * NHEAD + hh)) * TSEQ + t) * HDIM + d;
          __bf16 hb = (__bf16)v;
          obh[o] = hb;
          obl[o] = (__bf16)(v - (float)hb);
        }
      }
  } else {
#pragma unroll
    for (int i = 0; i < 2; ++i)
#pragma unroll
      for (int j = 0; j < 4; ++j) {
        int m = m0 + wm * 64 + j * 16 + a15;
        int bb = m >> 11, t = m & (TSEQ - 1);
#pragma unroll
        for (int r = 0; r < 4; ++r) {
          int n = n0 + wn * 32 + i * 16 + 4 * g + r;
          float v = acc[i][j][r] + bias[n];
          int hh = n >> 6, d = n & 63;
          size_t o = (((size_t)(bb * NHEAD + hh)) * HDIM + d) * TSEQ + t;
          __bf16 hb = (__bf16)v;
          obh[o] = hb;
          obl[o] = (__bf16)(v - (float)hb);
        }
      }
  }
}

// ---------------- Flash attention: 8 waves/block (512 thr), 128 q-rows/block ----------------
// Same per-wave algorithm as R6 (global_load_lds dbuf + counted vmcnt: no staging VGPRs,
// no spill). 8 waves now SHARE the same 64KB K/V dbuf -> 2 blocks/CU = 16 waves/CU =
// 4 waves/SIMD (2x R6) to hide the per-tile serial chain. Grid = 512 blocks = exactly 2/CU.
__global__ __launch_bounds__(512)
void attn_mfma(const bf16_t* __restrict__ Qhi, const bf16_t* __restrict__ Qlo,
               const bf16_t* __restrict__ Khi, const bf16_t* __restrict__ Klo,
               const bf16_t* __restrict__ Vth, const bf16_t* __restrict__ Vtl,
               const bf16_t* __restrict__ BMt, float* __restrict__ O) {
  __shared__ bf16_t KH[2][8 * 512], KL[2][8 * 512], VH[2][8 * 512], VL[2][8 * 512];  // 64 KiB
  const int tid = threadIdx.x;
  const int lane = tid & 63, wv = tid >> 6;          // wv = 0..7
  const int a15 = lane & 15, g = lane >> 4;
  const int b = blockIdx.z, h = blockIdx.y, q0 = blockIdx.x * 128;
  const int bh = b * NHEAD + h;
  const int qg = q0 + wv * 16 + a15;
  constexpr int NT = TSEQ / 64;

  const bf16_t* Qh_b = Qhi + ((size_t)bh * TSEQ + qg) * HDIM;
  const bf16_t* Ql_b = Qlo + ((size_t)bh * TSEQ + qg) * HDIM;
  const bf16_t* Kh_b = Khi + (size_t)bh * TSEQ * HDIM;
  const bf16_t* Kl_b = Klo + (size_t)bh * TSEQ * HDIM;
  const bf16_t* Vh_b = Vth + (size_t)bh * HDIM * TSEQ;
  const bf16_t* Vl_b = Vtl + (size_t)bh * HDIM * TSEQ;
  const bf16_t* bmrow = BMt + ((size_t)b * TSEQ + qg) * TSEQ;

  bf16x8 qh[2], ql[2];
  qh[0] = *(const bf16x8*)&Qh_b[8 * g];
  qh[1] = *(const bf16x8*)&Qh_b[32 + 8 * g];
  ql[0] = *(const bf16x8*)&Ql_b[8 * g];
  ql[1] = *(const bf16x8*)&Ql_b[32 + 8 * g];

  f32x4 aco[4] = {};
  float m_run = -3.0e38f, l_run = 0.f;
  bf16x4 bmv[4], bmn[4];

  // wave wv stages slot wv of each of the 4 arrays (4 gload16/wave/tile; 32 per block)
  const int ts = wv >> 1, ks = wv & 1;
  auto stage = [&](int k0, int buf) {
    size_t ko = (size_t)(k0 + 16 * ts + a15) * HDIM + 32 * ks + 8 * g;
    gload16(Kh_b + ko, &KH[buf][wv * 512]);
    gload16(Kl_b + ko, &KL[buf][wv * 512]);
    size_t vo = (size_t)(16 * ts + a15) * TSEQ + k0 + 32 * ks + 8 * g;
    gload16(Vh_b + vo, &VH[buf][wv * 512]);
    gload16(Vl_b + vo, &VL[buf][wv * 512]);
  };

  // prologue: bias tile 0 (4 loads) + K/V tile 0 (4 loads)
#pragma unroll
  for (int mt = 0; mt < 4; ++mt) bmv[mt] = *(const bf16x4*)&bmrow[16 * mt + 4 * g];
  stage(0, 0);

  for (int t = 0; t < NT; ++t) {
    const int cur = t & 1;
    if (t + 1 < NT) {
      const int kn = (t + 1) * 64;
      // next tile: 4 bias loads + 4 gload_lds = 8 vmem ops, stay in flight
#pragma unroll
      for (int mt = 0; mt < 4; ++mt) bmn[mt] = *(const bf16x4*)&bmrow[kn + 16 * mt + 4 * g];
      stage(kn, cur ^ 1);
      asm volatile("s_waitcnt vmcnt(8)" ::: "memory");  // drain PREVIOUS tile's 8 only
    } else {
      asm volatile("s_waitcnt vmcnt(0)" ::: "memory");
    }
    __builtin_amdgcn_sched_barrier(0);
    SBAR();                          // tile t's LDS data visible to all waves

    // --- S^T = K·Q (3-way split) ---
    f32x4 s4[4];
    __builtin_amdgcn_s_setprio(1);
#pragma unroll
    for (int mt = 0; mt < 4; ++mt) {
      bf16x8 k0h = *(const bf16x8*)&KH[cur][(mt * 2 + 0) * 512 + lane * 8];
      bf16x8 k1h = *(const bf16x8*)&KH[cur][(mt * 2 + 1) * 512 + lane * 8];
      bf16x8 k0l = *(const bf16x8*)&KL[cur][(mt * 2 + 0) * 512 + lane * 8];
      bf16x8 k1l = *(const bf16x8*)&KL[cur][(mt * 2 + 1) * 512 + lane * 8];
      f32x4 sa = {};
      sa = mfma16(k0h, qh[0], sa);
      sa = mfma16(k1h, qh[1], sa);
      sa = mfma16(k0h, ql[0], sa);
      sa = mfma16(k1h, ql[1], sa);
      sa = mfma16(k0l, qh[0], sa);
      sa = mfma16(k1l, qh[1], sa);
      s4[mt] = sa;
    }
    __builtin_amdgcn_s_setprio(0);

    // --- scores: fma with precomputed bias+mask table ---
#pragma unroll
    for (int mt = 0; mt < 4; ++mt)
#pragma unroll
      for (int r = 0; r < 4; ++r)
        s4[mt][r] = fmaf(s4[mt][r], 0.125f, (float)bmv[mt][r]);

    // --- online softmax with defer-rescale (T13) ---
    float tmax = -3.0e38f;
#pragma unroll
    for (int mt = 0; mt < 4; ++mt)
#pragma unroll
      for (int r = 0; r < 4; ++r) tmax = fmaxf(tmax, s4[mt][r]);
    tmax = fmaxf(tmax, __shfl_xor(tmax, 16));
    tmax = fmaxf(tmax, __shfl_xor(tmax, 32));
    if (!__all(tmax - m_run <= 8.0f)) {
      float mnew = fmaxf(m_run, tmax);
      float corr = __expf(m_run - mnew);
      l_run *= corr;
#pragma unroll
      for (int dt = 0; dt < 4; ++dt) aco[dt] *= corr;
      m_run = mnew;
    }
    float psum = 0.f;
    unsigned pk01[4], pk23[4];
#pragma unroll
    for (int mt = 0; mt < 4; ++mt) {
      float p0 = __expf(s4[mt][0] - m_run);
      float p1 = __expf(s4[mt][1] - m_run);
      float p2 = __expf(s4[mt][2] - m_run);
      float p3 = __expf(s4[mt][3] - m_run);
      psum += (p0 + p1) + (p2 + p3);
      pk01[mt] = pk2(p0, p1);
      pk23[mt] = pk2(p2, p3);
    }
    psum += __shfl_xor(psum, 16);
    psum += __shfl_xor(psum, 32);
    l_run += psum;

    // --- P -> B-frag layout: slot (g,j) holds key 32ks+8g+j of row q=a15 ---
    bf16x8 pf[2];
#pragma unroll
    for (int kss = 0; kss < 2; ++kss) {
      int src0 = a15 + 16 * (2 * (g & 1));
      int src1 = src0 + 16;
      unsigned A0 = __shfl(pk01[2 * kss + 0], src0), A1 = __shfl(pk01[2 * kss + 1], src0);
      unsigned B0 = __shfl(pk23[2 * kss + 0], src0), B1 = __shfl(pk23[2 * kss + 1], src0);
      unsigned C0 = __shfl(pk01[2 * kss + 0], src1), C1 = __shfl(pk01[2 * kss + 1], src1);
      unsigned D0 = __shfl(pk23[2 * kss + 0], src1), D1 = __shfl(pk23[2 * kss + 1], src1);
      bool hi2 = (g >> 1) & 1;
      uint4 wds;
      wds.x = hi2 ? A1 : A0;
      wds.y = hi2 ? B1 : B0;
      wds.z = hi2 ? C1 : C0;
      wds.w = hi2 ? D1 : D0;
      pf[kss] = __builtin_bit_cast(bf16x8, wds);
    }

    // --- O^T += Vt · P (V split hi/lo) ---
    __builtin_amdgcn_s_setprio(1);
#pragma unroll
    for (int dt = 0; dt < 4; ++dt) {
#pragma unroll
      for (int kss = 0; kss < 2; ++kss) {
        bf16x8 vh = *(const bf16x8*)&VH[cur][(dt * 2 + kss) * 512 + lane * 8];
        bf16x8 vl = *(const bf16x8*)&VL[cur][(dt * 2 + kss) * 512 + lane * 8];
        aco[dt] = mfma16(vh, pf[kss], aco[dt]);
        aco[dt] = mfma16(vl, pf[kss], aco[dt]);
      }
    }
    __builtin_amdgcn_s_setprio(0);

    if (t + 1 < NT) {
#pragma unroll
      for (int mt = 0; mt < 4; ++mt) bmv[mt] = bmn[mt];
    }
    SBAR();   // all waves done reading buf `cur` before next iter's stage overwrites it
  }

  float inv = 1.0f / l_run;
#pragma unroll
  for (int dt = 0; dt < 4; ++dt) {
    f32x4 o = aco[dt] * inv;
    *(f32x4*)&O[((size_t)b * TSEQ + qg) * DMODEL + h * HDIM + dt * 16 + 4 * g] = o;
  }
}

extern "C" void kernel_launch(void* const* d_in, const int* in_sizes, int n_in,
                              void* d_out, int out_size, void* d_ws, size_t ws_size,
                              hipStream_t stream) {
  const float* query = (const float*)d_in[0];
  const float* key = (const float*)d_in[1];
  const float* value = (const float*)d_in[2];
  const unsigned char* kpm = (const unsigned char*)d_in[3];
  const float* amask = (const float*)d_in[4];
  const float* sf = (const float*)d_in[5];
  const float* Wq = (const float*)d_in[6];
  const float* bq = (const float*)d_in[7];
  const float* Wk = (const float*)d_in[8];
  const float* bk = (const float*)d_in[9];
  const float* Wv = (const float*)d_in[10];
  const float* bv = (const float*)d_in[11];
  const float* Wo = (const float*)d_in[12];
  const float* bo = (const float*)d_in[13];
  const float* alpha = (const float*)d_in[14];
  float* out = (float*)d_out;

  const size_t NEL = (size_t)2 * NHEAD * TSEQ * HDIM;  // 4,194,304 per bf16 array
  bf16_t* p = (bf16_t*)d_ws;
  bf16_t* Qh = p;
  bf16_t* Ql = p + NEL;
  bf16_t* Kh = p + 2 * NEL;
  bf16_t* Kl = p + 3 * NEL;
  bf16_t* Vh = p + 4 * NEL;
  bf16_t* Vl = p + 5 * NEL;
  float* Oa = (float*)(p + 6 * NEL);                    // 16.8 MB
  bf16_t* BMt = (bf16_t*)(Oa + (size_t)4096 * DMODEL);  // 16.8 MB  (total 80 MiB)

  dim3 bb(256);
  build_bias<<<dim3(4096), bb, 0, stream>>>(amask, kpm, sf, alpha, BMt);

  dim3 gg(16, 32);
  gemm_mfma<1><<<gg, bb, 0, stream>>>(query, Wq, bq, Qh, Ql, nullptr);
  gemm_mfma<1><<<gg, bb, 0, stream>>>(key, Wk, bk, Kh, Kl, nullptr);
  gemm_mfma<2><<<gg, bb, 0, stream>>>(value, Wv, bv, Vh, Vl, nullptr);
  dim3 ga(TSEQ / 128, NHEAD, 2);   // (16, 16, 2) = 512 blocks
  attn_mfma<<<ga, dim3(512), 0, stream>>>(Qh, Ql, Kh, Kl, Vh, Vl, BMt, Oa);
  gemm_mfma<0><<<gg, bb, 0, stream>>>(Oa, Wo, bo, nullptr, nullptr, out);
}

// Round 9
// 338.670 us; speedup vs baseline: 1.7205x; 1.0036x over previous
//
#include <hip/hip_runtime.h>
#include <math.h>

typedef __bf16 bf16_t;
typedef __bf16 bf16x8 __attribute__((ext_vector_type(8)));
typedef __bf16 bf16x4 __attribute__((ext_vector_type(4)));
typedef float  f32x4  __attribute__((ext_vector_type(4)));

#define NHEAD 16
#define HDIM 64
#define DMODEL 1024
#define TSEQ 2048

#define SBAR() __builtin_amdgcn_s_barrier()
#define LGKM0() do { asm volatile("s_waitcnt lgkmcnt(0)" ::: "memory"); \
                     __builtin_amdgcn_sched_barrier(0); } while (0)

__device__ __forceinline__ f32x4 mfma16(bf16x8 a, bf16x8 b, f32x4 c) {
  return __builtin_amdgcn_mfma_f32_16x16x32_bf16(a, b, c, 0, 0, 0);
}

// async global->LDS, 16B per lane; lds base wave-uniform (HW adds lane*16)
__device__ __forceinline__ void gload16(const bf16_t* g, bf16_t* l) {
  __builtin_amdgcn_global_load_lds((const __attribute__((address_space(1))) void*)g,
                                   (__attribute__((address_space(3))) void*)l, 16, 0, 0);
}

// pack two f32 -> (bf16(hi)<<16)|bf16(lo)
__device__ __forceinline__ unsigned pk2(float lo, float hi) {
  unsigned short a = __builtin_bit_cast(unsigned short, (__bf16)lo);
  unsigned short c = __builtin_bit_cast(unsigned short, (__bf16)hi);
  return ((unsigned)c << 16) | a;
}

// split two f32x4 into hi/lo bf16x8 and store to frag-major LDS slot
__device__ __forceinline__ void cvtstore(f32x4 x0, f32x4 x1, bf16_t* dh, bf16_t* dl, int off) {
  bf16x8 hfr, lfr;
#pragma unroll
  for (int j = 0; j < 4; ++j) {
    float v = x0[j];
    __bf16 hb = (__bf16)v;
    hfr[j] = hb; lfr[j] = (__bf16)(v - (float)hb);
    float w = x1[j];
    __bf16 wb = (__bf16)w;
    hfr[4 + j] = wb; lfr[4 + j] = (__bf16)(w - (float)wb);
  }
  *(bf16x8*)(dh + off) = hfr;
  *(bf16x8*)(dl + off) = lfr;
}

// ---------------- bias table: BM[b][q][k] = alpha*copysign(log1p|df|,df) + amask[q][k] (+ -1e30 if kpm) ----------------
__global__ __launch_bounds__(256)
void build_bias(const float* __restrict__ amask, const unsigned char* __restrict__ kpm,
                const float* __restrict__ sf, const float* __restrict__ alpha_p,
                bf16_t* __restrict__ BM) {
  size_t idx = (size_t)blockIdx.x * 256 + threadIdx.x;
  int k8 = (int)(idx & (TSEQ / 8 - 1));
  size_t bq = idx >> 8;
  int b = (int)(bq >> 11);
  int q = (int)(bq & (TSEQ - 1));
  const float sfq = sf[bq];
  const float alpha = *alpha_p;
  const float* sfk = sf + (size_t)b * TSEQ + k8 * 8;
  const float* am  = amask + (size_t)q * TSEQ + k8 * 8;
  const unsigned char* kp = kpm + (size_t)b * TSEQ + k8 * 8;
  bf16x8 o;
#pragma unroll
  for (int j = 0; j < 8; ++j) {
    float df = sfq - sfk[j];
    float v = alpha * copysignf(log1pf(fabsf(df)), df) + am[j];
    if (kp[j]) v = -1.0e30f;
    o[j] = (__bf16)v;
  }
  *(bf16x8*)&BM[idx * 8] = o;
}

// ---------------- GEMM: C = A @ W^T + bias via bf16x3 split MFMA ----------------
// 512 threads (8 waves, 4m x 2n of 32x32 wave-tiles), 128x64 block tile, BK=32.
// 2 blocks/CU -> 16 waves/CU (2x the 4-wave version's occupancy).
// MODE 0: f32 out [M][1024]; MODE 1: bf16 hi/lo head layout [b][h][t][d]; MODE 2: V transposed [b][h][d][t]
template<int MODE>
__global__ __launch_bounds__(512)
void gemm_mfma(const float* __restrict__ A, const float* __restrict__ W,
               const float* __restrict__ bias,
               bf16_t* __restrict__ obh, bf16_t* __restrict__ obl,
               float* __restrict__ of) {
  __shared__ bf16_t AH[8 * 512], AL[8 * 512], WH[4 * 512], WL[4 * 512];  // 24 KiB
  const int tid = threadIdx.x;
  const int lane = tid & 63;
  const int a15 = lane & 15, g = lane >> 4;
  const int wv = tid >> 6, wm = wv >> 1, wn = wv & 1;   // 4 m-slices x 2 n-slices
  const int m0 = blockIdx.y * 128, n0 = blockIdx.x * 64;
  f32x4 acc[2][2] = {};

  // A staged by all 512 threads (slot tid of 512); W by tid<256 (slot tid of 256)
  const int t0 = tid >> 6, l0 = tid & 63;
  const float* pA0 = A + (size_t)(m0 + t0 * 16 + (l0 & 15)) * DMODEL + 8 * (l0 >> 4);
  const bool doW = (tid < 256);
  const int sW = tid & 255;
  const int tw = sW >> 6, lw = sW & 63;
  const float* pW = W + (size_t)(n0 + tw * 16 + (lw & 15)) * DMODEL + 8 * (lw >> 4);

  f32x4 rA0a = *(const f32x4*)pA0, rA0b = *(const f32x4*)(pA0 + 4);
  f32x4 rWa = {}, rWb = {};
  if (doW) { rWa = *(const f32x4*)pW; rWb = *(const f32x4*)(pW + 4); }

  for (int k0 = 0; k0 < DMODEL; k0 += 32) {
    SBAR();                          // prior step's LDS reads consumed (raw: no vmem drain)
    cvtstore(rA0a, rA0b, AH, AL, tid * 8);
    if (doW) cvtstore(rWa, rWb, WH, WL, sW * 8);
    __builtin_amdgcn_sched_barrier(0);
    if (k0 + 32 < DMODEL) {          // prefetch next K-step; survives the barriers below
      pA0 += 32;
      rA0a = *(const f32x4*)pA0; rA0b = *(const f32x4*)(pA0 + 4);
      if (doW) { pW += 32; rWa = *(const f32x4*)pW; rWb = *(const f32x4*)(pW + 4); }
    }
    LGKM0();                         // ds_writes committed
    SBAR();

    bf16x8 ah[2], al[2], wh[2], wl[2];
#pragma unroll
    for (int i = 0; i < 2; ++i) {
      ah[i] = *(const bf16x8*)&AH[(wm * 2 + i) * 512 + lane * 8];
      al[i] = *(const bf16x8*)&AL[(wm * 2 + i) * 512 + lane * 8];
      wh[i] = *(const bf16x8*)&WH[(wn * 2 + i) * 512 + lane * 8];
      wl[i] = *(const bf16x8*)&WL[(wn * 2 + i) * 512 + lane * 8];
    }
    __builtin_amdgcn_s_setprio(1);
    if (MODE == 2) {
#pragma unroll
      for (int i = 0; i < 2; ++i)
#pragma unroll
        for (int j = 0; j < 2; ++j) {
          acc[i][j] = mfma16(wh[i], ah[j], acc[i][j]);
          acc[i][j] = mfma16(wh[i], al[j], acc[i][j]);
          acc[i][j] = mfma16(wl[i], ah[j], acc[i][j]);
        }
    } else {
#pragma unroll
      for (int i = 0; i < 2; ++i)
#pragma unroll
        for (int j = 0; j < 2; ++j) {
          acc[i][j] = mfma16(ah[i], wh[j], acc[i][j]);
          acc[i][j] = mfma16(ah[i], wl[j], acc[i][j]);
          acc[i][j] = mfma16(al[i], wh[j], acc[i][j]);
        }
    }
    __builtin_amdgcn_s_setprio(0);
  }

  if (MODE == 0) {
#pragma unroll
    for (int i = 0; i < 2; ++i)
#pragma unroll
      for (int j = 0; j < 2; ++j) {
        int n = n0 + wn * 32 + j * 16 + a15;
        float bs = bias[n];
#pragma unroll
        for (int r = 0; r < 4; ++r) {
          int m = m0 + wm * 32 + i * 16 + 4 * g + r;
          of[(size_t)m * DMODEL + n] = acc[i][j][r] + bs;
        }
      }
  } else if (MODE == 1) {
#pragma unroll
    for (int i = 0; i < 2; ++i)
#pragma unroll
      for (int j = 0; j < 2; ++j) {
        int n = n0 + wn * 32 + j * 16 + a15;
        float bs = bias[n];
        int hh = n >> 6, d = n & 63;
#pragma unroll
        for (int r = 0; r < 4; ++r) {
          int m = m0 + wm * 32 + i * 16 + 4 * g + r;
          int bb = m >> 11, t = m & (TSEQ - 1);
          float v = acc[i][j][r] + bs;
          size_t o = (((size_t)(bb * NHEAD + hh)) * TSEQ + t) * HDIM + d;
          __bf16 hb = (__bf16)v;
          obh[o] = hb;
          obl[o] = (__bf16)(v - (float)hb);
        }
      }
  } else {
    // MODE2: D rows = W subtile (n-dim, i), D cols = A subtile (m-dim, j)
#pragma unroll
    for (int i = 0; i < 2; ++i)
#pragma unroll
      for (int j = 0; j < 2; ++j) {
        int m = m0 + wm * 32 + j * 16 + a15;
        int bb = m >> 11, t = m & (TSEQ - 1);
#pragma unroll
        for (int r = 0; r < 4; ++r) {
          int n = n0 + wn * 32 + i * 16 + 4 * g + r;
          float v = acc[i][j][r] + bias[n];
          int hh = n >> 6, d = n & 63;
          size_t o = (((size_t)(bb * NHEAD + hh)) * HDIM + d) * TSEQ + t;
          __bf16 hb = (__bf16)v;
          obh[o] = hb;
          obl[o] = (__bf16)(v - (float)hb);
        }
      }
  }
}

// ---------------- Flash attention: 8 waves/block (512 thr), 128 q-rows/block ----------------
// global_load_lds dbuf + counted vmcnt (no staging VGPRs, no spill). P redistribution
// via per-wave swizzled LDS scratch (4 ds_write_b64 + 2 ds_read_b128, intra-wave lgkm
// only) replaces 16 ds_bpermute shuffles + 8 cndmask on the per-tile serial chain.
__global__ __launch_bounds__(512)
void attn_mfma(const bf16_t* __restrict__ Qhi, const bf16_t* __restrict__ Qlo,
               const bf16_t* __restrict__ Khi, const bf16_t* __restrict__ Klo,
               const bf16_t* __restrict__ Vth, const bf16_t* __restrict__ Vtl,
               const bf16_t* __restrict__ BMt, float* __restrict__ O) {
  __shared__ bf16_t KH[2][8 * 512], KL[2][8 * 512], VH[2][8 * 512], VL[2][8 * 512];  // 64 KiB
  __shared__ bf16_t PS[8 * 512];     // per-wave P scratch: [8 waves][16 rows][32 keys] = 8 KiB
  const int tid = threadIdx.x;
  const int lane = tid & 63, wv = tid >> 6;          // wv = 0..7
  const int a15 = lane & 15, g = lane >> 4;
  const int b = blockIdx.z, h = blockIdx.y, q0 = blockIdx.x * 128;
  const int bh = b * NHEAD + h;
  const int qg = q0 + wv * 16 + a15;
  constexpr int NT = TSEQ / 64;

  const bf16_t* Qh_b = Qhi + ((size_t)bh * TSEQ + qg) * HDIM;
  const bf16_t* Ql_b = Qlo + ((size_t)bh * TSEQ + qg) * HDIM;
  const bf16_t* Kh_b = Khi + (size_t)bh * TSEQ * HDIM;
  const bf16_t* Kl_b = Klo + (size_t)bh * TSEQ * HDIM;
  const bf16_t* Vh_b = Vth + (size_t)bh * HDIM * TSEQ;
  const bf16_t* Vl_b = Vtl + (size_t)bh * HDIM * TSEQ;
  const bf16_t* bmrow = BMt + ((size_t)b * TSEQ + qg) * TSEQ;

  bf16x8 qh[2], ql[2];
  qh[0] = *(const bf16x8*)&Qh_b[8 * g];
  qh[1] = *(const bf16x8*)&Qh_b[32 + 8 * g];
  ql[0] = *(const bf16x8*)&Ql_b[8 * g];
  ql[1] = *(const bf16x8*)&Ql_b[32 + 8 * g];

  f32x4 aco[4] = {};
  float m_run = -3.0e38f, l_run = 0.f;
  bf16x4 bmv[4], bmn[4];

  // wave wv stages slot wv of each of the 4 arrays (4 gload16/wave/tile)
  const int ts = wv >> 1, ks = wv & 1;
  auto stage = [&](int k0, int buf) {
    size_t ko = (size_t)(k0 + 16 * ts + a15) * HDIM + 32 * ks + 8 * g;
    gload16(Kh_b + ko, &KH[buf][wv * 512]);
    gload16(Kl_b + ko, &KL[buf][wv * 512]);
    size_t vo = (size_t)(16 * ts + a15) * TSEQ + k0 + 32 * ks + 8 * g;
    gload16(Vh_b + vo, &VH[buf][wv * 512]);
    gload16(Vl_b + vo, &VL[buf][wv * 512]);
  };

  // prologue: bias tile 0 (4 loads) + K/V tile 0 (4 loads)
#pragma unroll
  for (int mt = 0; mt < 4; ++mt) bmv[mt] = *(const bf16x4*)&bmrow[16 * mt + 4 * g];
  stage(0, 0);

  for (int t = 0; t < NT; ++t) {
    const int cur = t & 1;
    if (t + 1 < NT) {
      const int kn = (t + 1) * 64;
      // next tile: 4 bias loads + 4 gload_lds = 8 vmem ops, stay in flight
#pragma unroll
      for (int mt = 0; mt < 4; ++mt) bmn[mt] = *(const bf16x4*)&bmrow[kn + 16 * mt + 4 * g];
      stage(kn, cur ^ 1);
      asm volatile("s_waitcnt vmcnt(8)" ::: "memory");  // drain PREVIOUS tile's 8 only
    } else {
      asm volatile("s_waitcnt vmcnt(0)" ::: "memory");
    }
    __builtin_amdgcn_sched_barrier(0);
    SBAR();                          // tile t's LDS data visible to all waves

    // --- S^T = K·Q (3-way split) ---
    f32x4 s4[4];
    __builtin_amdgcn_s_setprio(1);
#pragma unroll
    for (int mt = 0; mt < 4; ++mt) {
      bf16x8 k0h = *(const bf16x8*)&KH[cur][(mt * 2 + 0) * 512 + lane * 8];
      bf16x8 k1h = *(const bf16x8*)&KH[cur][(mt * 2 + 1) * 512 + lane * 8];
      bf16x8 k0l = *(const bf16x8*)&KL[cur][(mt * 2 + 0) * 512 + lane * 8];
      bf16x8 k1l = *(const bf16x8*)&KL[cur][(mt * 2 + 1) * 512 + lane * 8];
      f32x4 sa = {};
      sa = mfma16(k0h, qh[0], sa);
      sa = mfma16(k1h, qh[1], sa);
      sa = mfma16(k0h, ql[0], sa);
      sa = mfma16(k1h, ql[1], sa);
      sa = mfma16(k0l, qh[0], sa);
      sa = mfma16(k1l, qh[1], sa);
      s4[mt] = sa;
    }
    __builtin_amdgcn_s_setprio(0);

    // --- scores: fma with precomputed bias+mask table ---
#pragma unroll
    for (int mt = 0; mt < 4; ++mt)
#pragma unroll
      for (int r = 0; r < 4; ++r)
        s4[mt][r] = fmaf(s4[mt][r], 0.125f, (float)bmv[mt][r]);

    // --- online softmax with defer-rescale (T13) ---
    float tmax = -3.0e38f;
#pragma unroll
    for (int mt = 0; mt < 4; ++mt)
#pragma unroll
      for (int r = 0; r < 4; ++r) tmax = fmaxf(tmax, s4[mt][r]);
    tmax = fmaxf(tmax, __shfl_xor(tmax, 16));
    tmax = fmaxf(tmax, __shfl_xor(tmax, 32));
    if (!__all(tmax - m_run <= 8.0f)) {
      float mnew = fmaxf(m_run, tmax);
      float corr = __expf(m_run - mnew);
      l_run *= corr;
#pragma unroll
      for (int dt = 0; dt < 4; ++dt) aco[dt] *= corr;
      m_run = mnew;
    }
    float psum = 0.f;
    unsigned pk01[4], pk23[4];
#pragma unroll
    for (int mt = 0; mt < 4; ++mt) {
      float p0 = __expf(s4[mt][0] - m_run);
      float p1 = __expf(s4[mt][1] - m_run);
      float p2 = __expf(s4[mt][2] - m_run);
      float p3 = __expf(s4[mt][3] - m_run);
      psum += (p0 + p1) + (p2 + p3);
      pk01[mt] = pk2(p0, p1);
      pk23[mt] = pk2(p2, p3);
    }
    psum += __shfl_xor(psum, 16);
    psum += __shfl_xor(psum, 32);
    l_run += psum;

    // --- P -> B-frag via per-wave swizzled LDS scratch; PV interleaved per kss half ---
    // lane (a15,g) holds P[row=a15][key=16mt+4g+r]; B-frag needs 16B of keys 32kss+8g..+7
    // at row a15. Scratch layout per wave: [16 rows][4 x 16B slots], slot phys = s ^ (a15&3).
    const int psb = wv * 512 + a15 * 32;   // bf16-elem base (row a15)
    const int r3 = a15 & 3;
    __builtin_amdgcn_s_setprio(1);
#pragma unroll
    for (int kss = 0; kss < 2; ++kss) {
#pragma unroll
      for (int mh = 0; mh < 2; ++mh) {
        int mt = kss * 2 + mh;
        int phys = ((mh << 1) | (g >> 1)) ^ r3;
        uint2 w2;
        w2.x = pk01[mt];
        w2.y = pk23[mt];
        *(uint2*)&PS[psb + phys * 8 + (g & 1) * 4] = w2;
      }
      LGKM0();                        // intra-wave: writes visible to own lanes
      bf16x8 pf = *(const bf16x8*)&PS[psb + ((g ^ r3) << 3)];
#pragma unroll
      for (int dt = 0; dt < 4; ++dt) {
        bf16x8 vh = *(const bf16x8*)&VH[cur][(dt * 2 + kss) * 512 + lane * 8];
        bf16x8 vl = *(const bf16x8*)&VL[cur][(dt * 2 + kss) * 512 + lane * 8];
        aco[dt] = mfma16(vh, pf, aco[dt]);
        aco[dt] = mfma16(vl, pf, aco[dt]);
      }
    }
    __builtin_amdgcn_s_setprio(0);

    if (t + 1 < NT) {
#pragma unroll
      for (int mt = 0; mt < 4; ++mt) bmv[mt] = bmn[mt];
    }
    SBAR();   // all waves done reading buf `cur` before next iter's stage overwrites it
  }

  float inv = 1.0f / l_run;
#pragma unroll
  for (int dt = 0; dt < 4; ++dt) {
    f32x4 o = aco[dt] * inv;
    *(f32x4*)&O[((size_t)b * TSEQ + qg) * DMODEL + h * HDIM + dt * 16 + 4 * g] = o;
  }
}

extern "C" void kernel_launch(void* const* d_in, const int* in_sizes, int n_in,
                              void* d_out, int out_size, void* d_ws, size_t ws_size,
                              hipStream_t stream) {
  const float* query = (const float*)d_in[0];
  const float* key = (const float*)d_in[1];
  const float* value = (const float*)d_in[2];
  const unsigned char* kpm = (const unsigned char*)d_in[3];
  const float* amask = (const float*)d_in[4];
  const float* sf = (const float*)d_in[5];
  const float* Wq = (const float*)d_in[6];
  const float* bq = (const float*)d_in[7];
  const float* Wk = (const float*)d_in[8];
  const float* bk = (const float*)d_in[9];
  const float* Wv = (const float*)d_in[10];
  const float* bv = (const float*)d_in[11];
  const float* Wo = (const float*)d_in[12];
  const float* bo = (const float*)d_in[13];
  const float* alpha = (const float*)d_in[14];
  float* out = (float*)d_out;

  const size_t NEL = (size_t)2 * NHEAD * TSEQ * HDIM;  // 4,194,304 per bf16 array
  bf16_t* p = (bf16_t*)d_ws;
  bf16_t* Qh = p;
  bf16_t* Ql = p + NEL;
  bf16_t* Kh = p + 2 * NEL;
  bf16_t* Kl = p + 3 * NEL;
  bf16_t* Vh = p + 4 * NEL;
  bf16_t* Vl = p + 5 * NEL;
  float* Oa = (float*)(p + 6 * NEL);                    // 16.8 MB
  bf16_t* BMt = (bf16_t*)(Oa + (size_t)4096 * DMODEL);  // 16.8 MB  (total 80 MiB)

  build_bias<<<dim3(4096), dim3(256), 0, stream>>>(amask, kpm, sf, alpha, BMt);

  dim3 gg(16, 32), gb(512);
  gemm_mfma<1><<<gg, gb, 0, stream>>>(query, Wq, bq, Qh, Ql, nullptr);
  gemm_mfma<1><<<gg, gb, 0, stream>>>(key, Wk, bk, Kh, Kl, nullptr);
  gemm_mfma<2><<<gg, gb, 0, stream>>>(value, Wv, bv, Vh, Vl, nullptr);
  dim3 ga(TSEQ / 128, NHEAD, 2);   // (16, 16, 2) = 512 blocks
  attn_mfma<<<ga, dim3(512), 0, stream>>>(Qh, Ql, Kh, Kl, Vh, Vl, BMt, Oa);
  gemm_mfma<0><<<gg, gb, 0, stream>>>(Oa, Wo, bo, nullptr, nullptr, out);
}